// Round 1
// baseline (429.834 us; speedup 1.0000x reference)
//
#include <hip/hip_runtime.h>
#include <math.h>

#define A 5
#define S 1024
#define T 1024
#define KCH 8
#define B0 128
#define L 8192
#define EPSF 1e-12f

__device__ __forceinline__ float sigmoidf_(float x) {
    return 1.0f / (1.0f + __expf(-x));
}

// K1: BKT forward filter. One thread per (ability, subsequence) pair.
__global__ __launch_bounds__(256) void bkt_filter_kernel(
    const float* __restrict__ dyn_logits,   // [50][3]
    const float* __restrict__ obs_kc,       // [50][2]
    const float* __restrict__ obs_prob,     // [1000][2]
    const float* __restrict__ abil,         // [5]
    const int*   __restrict__ trial,        // [S][T]
    const int*   __restrict__ problem,      // [S][T]
    const int*   __restrict__ correct,      // [S][T]
    const int*   __restrict__ kc,           // [S]
    float* __restrict__ result,             // [A][S][T][2]
    float* __restrict__ obsll)              // [A][B0][L]
{
    int gid = blockIdx.x * blockDim.x + threadIdx.x;
    if (gid >= A * S) return;
    int a = gid >> 10;          // ability index
    int s = gid & (S - 1);      // subsequence index

    float ability = abil[a];
    int kcs = kc[s];
    float pL = sigmoidf_(dyn_logits[kcs * 3 + 0]);
    float pF = sigmoidf_(dyn_logits[kcs * 3 + 1]);
    float pI = sigmoidf_(dyn_logits[kcs * 3 + 2]);
    float ok0 = obs_kc[kcs * 2 + 0];
    float ok1 = obs_kc[kcs * 2 + 1];

    float a0 = 1.0f - pI, a1 = pI;          // alpha (normalized)
    float t00 = 1.0f - pL, t01 = pF, t10 = pL, t11 = 1.0f - pF;

    int b  = s >> 3;            // student
    int l0 = (s & 7) * T;       // timeline base within student

    const int* prob_row = problem + (size_t)s * T;
    const int* corr_row = correct + (size_t)s * T;
    const int* tid_row  = trial   + (size_t)s * T;
    float* res_row = result + (size_t)gid * T * 2;
    float* ll_row  = obsll + ((size_t)a * B0 + b) * L + l0;

    #pragma unroll 4
    for (int t = 0; t < T; ++t) {
        int p = prob_row[t];
        int c = corr_row[t];
        bool valid = (tid_row[t] != -1);

        float pG = sigmoidf_(ok0 + obs_prob[p * 2 + 0] + ability); // p(correct|not known)
        float pS = sigmoidf_(ok1 + obs_prob[p * 2 + 1] - ability); // p(incorrect|known)
        float pc0 = pG, pc1 = 1.0f - pS;

        float p_corr = a0 * pc0 + a1 * pc1;
        float lp1 = __logf(fmaxf(p_corr, EPSF));
        float lp0 = __logf(fmaxf(1.0f - p_corr, EPSF));

        float lik0 = c ? pc0 : (1.0f - pc0);
        float lik1 = c ? pc1 : (1.0f - pc1);
        float q0 = a0 * lik0, q1 = a1 * lik1;
        float inv = 1.0f / fmaxf(q0 + q1, EPSF);
        q0 *= inv; q1 *= inv;
        a0 = q0 * t00 + q1 * t01;
        a1 = q0 * t10 + q1 * t11;

        float w0 = valid ? lp0 : 0.0f;
        float w1 = valid ? lp1 : 0.0f;
        res_row[2 * t]     = w0;
        res_row[2 * t + 1] = w1;
        ll_row[t] = valid ? (c ? lp1 : lp0) : 0.0f;
    }
}

// K2: in-place exclusive prefix sum over L=8192 per (ability, student) row.
__global__ __launch_bounds__(256) void prefix_scan_kernel(float* __restrict__ obsll)
{
    __shared__ float sums[256];
    int row = blockIdx.x;                 // a*B0 + b
    float* base = obsll + (size_t)row * L;
    int tid = threadIdx.x;

    float v[32];
    float s = 0.0f;
    float* p = base + tid * 32;
    #pragma unroll
    for (int i = 0; i < 8; ++i) {
        float4 f = reinterpret_cast<const float4*>(p)[i];
        v[4*i+0] = f.x; v[4*i+1] = f.y; v[4*i+2] = f.z; v[4*i+3] = f.w;
        s += f.x + f.y + f.z + f.w;
    }
    sums[tid] = s;
    __syncthreads();
    // Hillis-Steele inclusive scan over 256 thread sums
    for (int off = 1; off < 256; off <<= 1) {
        float x = sums[tid];
        float y = (tid >= off) ? sums[tid - off] : 0.0f;
        __syncthreads();
        sums[tid] = x + y;
        __syncthreads();
    }
    float run = sums[tid] - s;   // exclusive base for this thread
    #pragma unroll
    for (int i = 0; i < 32; ++i) {
        p[i] = run;
        run += v[i];
    }
}

// K3: per (student, timeline-slot): ability mixture via logsumexp.
__global__ __launch_bounds__(256) void combine_kernel(
    const float* __restrict__ result,   // [A][S][T][2]
    const float* __restrict__ prefix,   // [A][B0][L] (exclusive cumsum)
    float* __restrict__ out)            // [B0][L][2]
{
    int gid = blockIdx.x * blockDim.x + threadIdx.x;
    if (gid >= B0 * L) return;
    int b = gid >> 13;
    int l = gid & (L - 1);

    float pf[A];
    float m = -INFINITY;
    #pragma unroll
    for (int a = 0; a < A; ++a) {
        pf[a] = prefix[((size_t)a * B0 + b) * L + l];
        m = fmaxf(m, pf[a]);
    }
    float sum = 0.0f;
    #pragma unroll
    for (int a = 0; a < A; ++a) sum += __expf(pf[a] - m);
    float lse = m + __logf(sum);

    int s = b * KCH + (l >> 10);
    int t = l & (T - 1);
    float r0[A], r1[A];
    #pragma unroll
    for (int a = 0; a < A; ++a) {
        const float* rp = result + (((size_t)a * S + s) * T + t) * 2;
        r0[a] = rp[0];
        r1[a] = rp[1];
    }
    float m0 = -INFINITY, m1 = -INFINITY;
    #pragma unroll
    for (int a = 0; a < A; ++a) {
        float w = pf[a] - lse;
        r0[a] += w; r1[a] += w;
        m0 = fmaxf(m0, r0[a]);
        m1 = fmaxf(m1, r1[a]);
    }
    float s0 = 0.0f, s1 = 0.0f;
    #pragma unroll
    for (int a = 0; a < A; ++a) {
        s0 += __expf(r0[a] - m0);
        s1 += __expf(r1[a] - m1);
    }
    out[2 * gid]     = m0 + __logf(s0);
    out[2 * gid + 1] = m1 + __logf(s1);
}

extern "C" void kernel_launch(void* const* d_in, const int* in_sizes, int n_in,
                              void* d_out, int out_size, void* d_ws, size_t ws_size,
                              hipStream_t stream) {
    const float* dyn  = (const float*)d_in[0];
    const float* okc  = (const float*)d_in[1];
    const float* oprb = (const float*)d_in[2];
    const float* ab   = (const float*)d_in[3];
    const int* trial  = (const int*)d_in[4];
    const int* prob   = (const int*)d_in[5];
    const int* corr   = (const int*)d_in[6];
    const int* kc     = (const int*)d_in[7];
    // d_in[8] (ytrue) not needed: validity/correctness derivable from trial/correct.
    float* out = (float*)d_out;

    float* result = (float*)d_ws;                       // A*S*T*2 floats = 42 MB
    float* obsll  = result + (size_t)A * S * T * 2;     // A*B0*L floats = 21 MB

    bkt_filter_kernel<<<(A * S + 255) / 256, 256, 0, stream>>>(
        dyn, okc, oprb, ab, trial, prob, corr, kc, result, obsll);
    prefix_scan_kernel<<<A * B0, 256, 0, stream>>>(obsll);
    combine_kernel<<<(B0 * L + 255) / 256, 256, 0, stream>>>(result, obsll, out);
}

// Round 2
// 65.684 us; speedup vs baseline: 6.5439x; 6.5439x over previous
//
#include <hip/hip_runtime.h>
#include <math.h>

#define A 5
#define S 1024
#define T 1024
#define KCH 8
#define B0 128
#define L 8192
#define NPROB 1000
#define EPSF 1e-12f
#define CHUNK 16               // time steps per lane
#define WPB 4                  // waves (pairs) per block

__device__ __forceinline__ float sigmoidf_(float x) {
    return 1.0f / (1.0f + __expf(-x));
}

// K1: BKT forward filter via wave-parallel 2x2-matrix scan.
// One wave per (ability, subsequence) pair; lane i owns steps [16i, 16i+16).
__global__ __launch_bounds__(256) void bkt_filter_kernel(
    const float* __restrict__ dyn_logits,   // [50][3]
    const float* __restrict__ obs_kc,       // [50][2]
    const float* __restrict__ obs_prob,     // [1000][2]
    const float* __restrict__ abil,         // [5]
    const int*   __restrict__ trial,        // [S][T]
    const int*   __restrict__ problem,      // [S][T]
    const int*   __restrict__ correct,      // [S][T]
    const int*   __restrict__ kc,           // [S]
    float* __restrict__ result,             // [A][S][T][2]
    float* __restrict__ obsll)              // [A][B0][L]
{
    __shared__ float s_op[2 * NPROB];       // 8 KB problem-logit table
    for (int i = threadIdx.x; i < 2 * NPROB; i += 256)
        s_op[i] = obs_prob[i];
    __syncthreads();

    int wave = threadIdx.x >> 6;
    int lane = threadIdx.x & 63;
    int pair = blockIdx.x * WPB + wave;     // < A*S always (1280*4 == 5120)
    int a = pair >> 10;
    int s = pair & (S - 1);

    float ability = abil[a];
    int kcs = kc[s];
    float pL = sigmoidf_(dyn_logits[kcs * 3 + 0]);
    float pF = sigmoidf_(dyn_logits[kcs * 3 + 1]);
    float pI = sigmoidf_(dyn_logits[kcs * 3 + 2]);
    float ok0 = obs_kc[kcs * 2 + 0];
    float ok1 = obs_kc[kcs * 2 + 1];
    float t00 = 1.0f - pL, t01 = pF, t10 = pL, t11 = 1.0f - pF;

    int t0 = lane * CHUNK;
    const int4* pv4 = (const int4*)(problem + (size_t)s * T + t0);
    const int4* cv4 = (const int4*)(correct + (size_t)s * T + t0);
    const int4* tv4 = (const int4*)(trial   + (size_t)s * T + t0);
    int4 pv[4], cv[4], tv[4];
    #pragma unroll
    for (int i = 0; i < 4; ++i) { pv[i] = pv4[i]; cv[i] = cv4[i]; tv[i] = tv4[i]; }

    int pj[16];
    int cmask = 0, vmask = 0;
    #pragma unroll
    for (int i = 0; i < 4; ++i) {
        pj[4*i+0] = pv[i].x; pj[4*i+1] = pv[i].y; pj[4*i+2] = pv[i].z; pj[4*i+3] = pv[i].w;
        cmask |= (cv[i].x & 1) << (4*i+0);
        cmask |= (cv[i].y & 1) << (4*i+1);
        cmask |= (cv[i].z & 1) << (4*i+2);
        cmask |= (cv[i].w & 1) << (4*i+3);
        vmask |= (tv[i].x != -1) << (4*i+0);
        vmask |= (tv[i].y != -1) << (4*i+1);
        vmask |= (tv[i].z != -1) << (4*i+2);
        vmask |= (tv[i].w != -1) << (4*i+3);
    }

    // ---- Phase 1: per-lane chunk matrix product (renormalized each step) ----
    float pc0a[16], pc1a[16];
    float p00 = 1.0f, p01 = 0.0f, p10 = 0.0f, p11 = 1.0f;
    #pragma unroll
    for (int j = 0; j < 16; ++j) {
        int p = pj[j];
        bool c = (cmask >> j) & 1;
        float pG = sigmoidf_(ok0 + s_op[2*p]   + ability);
        float pS = sigmoidf_(ok1 + s_op[2*p+1] - ability);
        float pc0 = pG, pc1 = 1.0f - pS;
        pc0a[j] = pc0; pc1a[j] = pc1;
        float lik0 = c ? pc0 : 1.0f - pc0;
        float lik1 = c ? pc1 : 1.0f - pc1;
        // M = T^T * diag(lik);  P <- M * P
        float r0 = lik0 * p00, r1 = lik1 * p10;
        float r2 = lik0 * p01, r3 = lik1 * p11;
        float n00 = t00 * r0 + t01 * r1;
        float n10 = t10 * r0 + t11 * r1;
        float n01 = t00 * r2 + t01 * r3;
        float n11 = t10 * r2 + t11 * r3;
        float inv = 1.0f / (n00 + n01 + n10 + n11);
        p00 = n00 * inv; p01 = n01 * inv; p10 = n10 * inv; p11 = n11 * inv;
    }

    // ---- Phase 2: inclusive shuffle-scan of matrix products over 64 lanes ----
    float q00 = p00, q01 = p01, q10 = p10, q11 = p11;
    #pragma unroll
    for (int off = 1; off < 64; off <<= 1) {
        float o00 = __shfl_up(q00, off);
        float o01 = __shfl_up(q01, off);
        float o10 = __shfl_up(q10, off);
        float o11 = __shfl_up(q11, off);
        if (lane >= off) {
            float n00 = q00 * o00 + q01 * o10;
            float n01 = q00 * o01 + q01 * o11;
            float n10 = q10 * o00 + q11 * o10;
            float n11 = q10 * o01 + q11 * o11;
            float inv = 1.0f / (n00 + n01 + n10 + n11);
            q00 = n00 * inv; q01 = n01 * inv; q10 = n10 * inv; q11 = n11 * inv;
        }
    }
    // exclusive prefix -> alpha at chunk start
    float e00 = __shfl_up(q00, 1), e01 = __shfl_up(q01, 1);
    float e10 = __shfl_up(q10, 1), e11 = __shfl_up(q11, 1);
    if (lane == 0) { e00 = 1.0f; e01 = 0.0f; e10 = 0.0f; e11 = 1.0f; }
    float a0 = e00 * (1.0f - pI) + e01 * pI;
    float a1 = e10 * (1.0f - pI) + e11 * pI;
    {
        float inv = 1.0f / fmaxf(a0 + a1, EPSF);
        a0 *= inv; a1 *= inv;
    }

    // ---- Phase 3: replay chunk, emit log-predictions (reuse pc arrays) ----
    #pragma unroll
    for (int j = 0; j < 16; ++j) {
        float pc0 = pc0a[j], pc1 = pc1a[j];
        bool c = (cmask >> j) & 1;
        bool valid = (vmask >> j) & 1;
        float p_corr = a0 * pc0 + a1 * pc1;
        float lp1 = __logf(fmaxf(p_corr, EPSF));
        float lp0 = __logf(fmaxf(1.0f - p_corr, EPSF));
        pc0a[j] = valid ? lp0 : 0.0f;
        pc1a[j] = valid ? lp1 : 0.0f;
        float lik0 = c ? pc0 : 1.0f - pc0;
        float lik1 = c ? pc1 : 1.0f - pc1;
        float qq0 = a0 * lik0, qq1 = a1 * lik1;
        float invq = 1.0f / fmaxf(qq0 + qq1, EPSF);
        qq0 *= invq; qq1 *= invq;
        a0 = qq0 * t00 + qq1 * t01;
        a1 = qq0 * t10 + qq1 * t11;
    }

    // ---- coalesced float4 writes ----
    float* res_row = result + (((size_t)pair) * T + t0) * 2;
    #pragma unroll
    for (int k = 0; k < 8; ++k) {
        float4 w = make_float4(pc0a[2*k], pc1a[2*k], pc0a[2*k+1], pc1a[2*k+1]);
        ((float4*)res_row)[k] = w;
    }
    int b = s >> 3;
    int l0 = (s & 7) * T;
    float* ll_row = obsll + ((size_t)a * B0 + b) * L + l0 + t0;
    #pragma unroll
    for (int k = 0; k < 4; ++k) {
        float4 w;
        w.x = ((cmask >> (4*k+0)) & 1) ? pc1a[4*k+0] : pc0a[4*k+0];
        w.y = ((cmask >> (4*k+1)) & 1) ? pc1a[4*k+1] : pc0a[4*k+1];
        w.z = ((cmask >> (4*k+2)) & 1) ? pc1a[4*k+2] : pc0a[4*k+2];
        w.w = ((cmask >> (4*k+3)) & 1) ? pc1a[4*k+3] : pc0a[4*k+3];
        ((float4*)ll_row)[k] = w;
    }
}

// K2: in-place exclusive prefix sum over L=8192 per (ability, student) row.
__global__ __launch_bounds__(256) void prefix_scan_kernel(float* __restrict__ obsll)
{
    __shared__ float sums[256];
    int row = blockIdx.x;                 // a*B0 + b
    float* base = obsll + (size_t)row * L;
    int tid = threadIdx.x;

    float v[32];
    float s = 0.0f;
    float* p = base + tid * 32;
    #pragma unroll
    for (int i = 0; i < 8; ++i) {
        float4 f = reinterpret_cast<const float4*>(p)[i];
        v[4*i+0] = f.x; v[4*i+1] = f.y; v[4*i+2] = f.z; v[4*i+3] = f.w;
        s += f.x + f.y + f.z + f.w;
    }
    sums[tid] = s;
    __syncthreads();
    for (int off = 1; off < 256; off <<= 1) {
        float x = sums[tid];
        float y = (tid >= off) ? sums[tid - off] : 0.0f;
        __syncthreads();
        sums[tid] = x + y;
        __syncthreads();
    }
    float run = sums[tid] - s;   // exclusive base for this thread
    #pragma unroll
    for (int i = 0; i < 32; ++i) {
        p[i] = run;
        run += v[i];
    }
}

// K3: per (student, timeline-slot): ability mixture via logsumexp.
__global__ __launch_bounds__(256) void combine_kernel(
    const float* __restrict__ result,   // [A][S][T][2]
    const float* __restrict__ prefix,   // [A][B0][L] (exclusive cumsum)
    float* __restrict__ out)            // [B0][L][2]
{
    int gid = blockIdx.x * blockDim.x + threadIdx.x;
    if (gid >= B0 * L) return;
    int b = gid >> 13;
    int l = gid & (L - 1);

    float pf[A];
    float m = -INFINITY;
    #pragma unroll
    for (int a = 0; a < A; ++a) {
        pf[a] = prefix[((size_t)a * B0 + b) * L + l];
        m = fmaxf(m, pf[a]);
    }
    float sum = 0.0f;
    #pragma unroll
    for (int a = 0; a < A; ++a) sum += __expf(pf[a] - m);
    float lse = m + __logf(sum);

    int s = b * KCH + (l >> 10);
    int t = l & (T - 1);
    float r0[A], r1[A];
    #pragma unroll
    for (int a = 0; a < A; ++a) {
        const float* rp = result + (((size_t)a * S + s) * T + t) * 2;
        r0[a] = rp[0];
        r1[a] = rp[1];
    }
    float m0 = -INFINITY, m1 = -INFINITY;
    #pragma unroll
    for (int a = 0; a < A; ++a) {
        float w = pf[a] - lse;
        r0[a] += w; r1[a] += w;
        m0 = fmaxf(m0, r0[a]);
        m1 = fmaxf(m1, r1[a]);
    }
    float s0 = 0.0f, s1 = 0.0f;
    #pragma unroll
    for (int a = 0; a < A; ++a) {
        s0 += __expf(r0[a] - m0);
        s1 += __expf(r1[a] - m1);
    }
    out[2 * gid]     = m0 + __logf(s0);
    out[2 * gid + 1] = m1 + __logf(s1);
}

extern "C" void kernel_launch(void* const* d_in, const int* in_sizes, int n_in,
                              void* d_out, int out_size, void* d_ws, size_t ws_size,
                              hipStream_t stream) {
    const float* dyn  = (const float*)d_in[0];
    const float* okc  = (const float*)d_in[1];
    const float* oprb = (const float*)d_in[2];
    const float* ab   = (const float*)d_in[3];
    const int* trial  = (const int*)d_in[4];
    const int* prob   = (const int*)d_in[5];
    const int* corr   = (const int*)d_in[6];
    const int* kc     = (const int*)d_in[7];
    float* out = (float*)d_out;

    float* result = (float*)d_ws;                       // A*S*T*2 floats = 42 MB
    float* obsll  = result + (size_t)A * S * T * 2;     // A*B0*L floats = 21 MB

    bkt_filter_kernel<<<(A * S) / WPB, 256, 0, stream>>>(
        dyn, okc, oprb, ab, trial, prob, corr, kc, result, obsll);
    prefix_scan_kernel<<<A * B0, 256, 0, stream>>>(obsll);
    combine_kernel<<<(B0 * L + 255) / 256, 256, 0, stream>>>(result, obsll, out);
}

// Round 3
// 48.530 us; speedup vs baseline: 8.8571x; 1.3535x over previous
//
#include <hip/hip_runtime.h>
#include <hip/hip_fp16.h>
#include <math.h>

#define A 5
#define S 1024
#define T 1024
#define KCH 8
#define B0 128
#define L 8192
#define NPROB 1000
#define EPSF 1e-12f
#define CHUNK 16               // time steps per lane
#define WPB 4                  // waves (pairs) per block

__device__ __forceinline__ float sigmoidf_(float x) {
    return 1.0f / (1.0f + __expf(-x));
}

union H2U { unsigned u; __half2 h; };

// K1: BKT forward filter via wave-parallel 2x2-matrix scan.
// One wave per (ability, subsequence) pair; lane i owns steps [16i, 16i+16).
// result stored as half2 (lp0, lp1) per trial.
__global__ __launch_bounds__(256) void bkt_filter_kernel(
    const float* __restrict__ dyn_logits,   // [50][3]
    const float* __restrict__ obs_kc,       // [50][2]
    const float* __restrict__ obs_prob,     // [1000][2]
    const float* __restrict__ abil,         // [5]
    const int*   __restrict__ trial,        // [S][T]
    const int*   __restrict__ problem,      // [S][T]
    const int*   __restrict__ correct,      // [S][T]
    const int*   __restrict__ kc,           // [S]
    __half2* __restrict__ result,           // [A][S][T]
    float* __restrict__ obsll)              // [A][B0][L]
{
    __shared__ float s_op[2 * NPROB];       // 8 KB problem-logit table
    for (int i = threadIdx.x; i < 2 * NPROB; i += 256)
        s_op[i] = obs_prob[i];
    __syncthreads();

    int wave = threadIdx.x >> 6;
    int lane = threadIdx.x & 63;
    int pair = blockIdx.x * WPB + wave;     // < A*S always (1280*4 == 5120)
    int a = pair >> 10;
    int s = pair & (S - 1);

    float ability = abil[a];
    int kcs = kc[s];
    float pL = sigmoidf_(dyn_logits[kcs * 3 + 0]);
    float pF = sigmoidf_(dyn_logits[kcs * 3 + 1]);
    float pI = sigmoidf_(dyn_logits[kcs * 3 + 2]);
    float ok0 = obs_kc[kcs * 2 + 0];
    float ok1 = obs_kc[kcs * 2 + 1];
    float t00 = 1.0f - pL, t01 = pF, t10 = pL, t11 = 1.0f - pF;

    int t0 = lane * CHUNK;
    const int4* pv4 = (const int4*)(problem + (size_t)s * T + t0);
    const int4* cv4 = (const int4*)(correct + (size_t)s * T + t0);
    const int4* tv4 = (const int4*)(trial   + (size_t)s * T + t0);
    int4 pv[4], cv[4], tv[4];
    #pragma unroll
    for (int i = 0; i < 4; ++i) { pv[i] = pv4[i]; cv[i] = cv4[i]; tv[i] = tv4[i]; }

    int pj[16];
    int cmask = 0, vmask = 0;
    #pragma unroll
    for (int i = 0; i < 4; ++i) {
        pj[4*i+0] = pv[i].x; pj[4*i+1] = pv[i].y; pj[4*i+2] = pv[i].z; pj[4*i+3] = pv[i].w;
        cmask |= (cv[i].x & 1) << (4*i+0);
        cmask |= (cv[i].y & 1) << (4*i+1);
        cmask |= (cv[i].z & 1) << (4*i+2);
        cmask |= (cv[i].w & 1) << (4*i+3);
        vmask |= (tv[i].x != -1) << (4*i+0);
        vmask |= (tv[i].y != -1) << (4*i+1);
        vmask |= (tv[i].z != -1) << (4*i+2);
        vmask |= (tv[i].w != -1) << (4*i+3);
    }

    // ---- Phase 1: per-lane chunk matrix product (renormalized each step) ----
    float pc0a[16], pc1a[16];
    float p00 = 1.0f, p01 = 0.0f, p10 = 0.0f, p11 = 1.0f;
    #pragma unroll
    for (int j = 0; j < 16; ++j) {
        int p = pj[j];
        bool c = (cmask >> j) & 1;
        float pG = sigmoidf_(ok0 + s_op[2*p]   + ability);
        float pS = sigmoidf_(ok1 + s_op[2*p+1] - ability);
        float pc0 = pG, pc1 = 1.0f - pS;
        pc0a[j] = pc0; pc1a[j] = pc1;
        float lik0 = c ? pc0 : 1.0f - pc0;
        float lik1 = c ? pc1 : 1.0f - pc1;
        // M = T^T * diag(lik);  P <- M * P
        float r0 = lik0 * p00, r1 = lik1 * p10;
        float r2 = lik0 * p01, r3 = lik1 * p11;
        float n00 = t00 * r0 + t01 * r1;
        float n10 = t10 * r0 + t11 * r1;
        float n01 = t00 * r2 + t01 * r3;
        float n11 = t10 * r2 + t11 * r3;
        float inv = __builtin_amdgcn_rcpf(n00 + n01 + n10 + n11);
        p00 = n00 * inv; p01 = n01 * inv; p10 = n10 * inv; p11 = n11 * inv;
    }

    // ---- Phase 2: inclusive shuffle-scan of matrix products over 64 lanes ----
    float q00 = p00, q01 = p01, q10 = p10, q11 = p11;
    #pragma unroll
    for (int off = 1; off < 64; off <<= 1) {
        float o00 = __shfl_up(q00, off);
        float o01 = __shfl_up(q01, off);
        float o10 = __shfl_up(q10, off);
        float o11 = __shfl_up(q11, off);
        if (lane >= off) {
            float n00 = q00 * o00 + q01 * o10;
            float n01 = q00 * o01 + q01 * o11;
            float n10 = q10 * o00 + q11 * o10;
            float n11 = q10 * o01 + q11 * o11;
            float inv = __builtin_amdgcn_rcpf(n00 + n01 + n10 + n11);
            q00 = n00 * inv; q01 = n01 * inv; q10 = n10 * inv; q11 = n11 * inv;
        }
    }
    // exclusive prefix -> alpha at chunk start
    float e00 = __shfl_up(q00, 1), e01 = __shfl_up(q01, 1);
    float e10 = __shfl_up(q10, 1), e11 = __shfl_up(q11, 1);
    if (lane == 0) { e00 = 1.0f; e01 = 0.0f; e10 = 0.0f; e11 = 1.0f; }
    float a0 = e00 * (1.0f - pI) + e01 * pI;
    float a1 = e10 * (1.0f - pI) + e11 * pI;
    {
        float inv = __builtin_amdgcn_rcpf(fmaxf(a0 + a1, EPSF));
        a0 *= inv; a1 *= inv;
    }

    // ---- Phase 3: replay chunk, emit log-predictions (reuse pc arrays) ----
    #pragma unroll
    for (int j = 0; j < 16; ++j) {
        float pc0 = pc0a[j], pc1 = pc1a[j];
        bool c = (cmask >> j) & 1;
        bool valid = (vmask >> j) & 1;
        float p_corr = a0 * pc0 + a1 * pc1;
        float lp1 = __logf(fmaxf(p_corr, EPSF));
        float lp0 = __logf(fmaxf(1.0f - p_corr, EPSF));
        pc0a[j] = valid ? lp0 : 0.0f;
        pc1a[j] = valid ? lp1 : 0.0f;
        float lik0 = c ? pc0 : 1.0f - pc0;
        float lik1 = c ? pc1 : 1.0f - pc1;
        float qq0 = a0 * lik0, qq1 = a1 * lik1;
        float invq = __builtin_amdgcn_rcpf(fmaxf(qq0 + qq1, EPSF));
        qq0 *= invq; qq1 *= invq;
        a0 = qq0 * t00 + qq1 * t01;
        a1 = qq0 * t10 + qq1 * t11;
    }

    // ---- coalesced writes: result as packed half2, obsll as float4 ----
    unsigned ru[16];
    #pragma unroll
    for (int j = 0; j < 16; ++j) {
        H2U cv_;
        cv_.h = __floats2half2_rn(pc0a[j], pc1a[j]);
        ru[j] = cv_.u;
    }
    __half2* res_row = result + ((size_t)pair * T + t0);
    #pragma unroll
    for (int k = 0; k < 4; ++k) {
        uint4 w = make_uint4(ru[4*k], ru[4*k+1], ru[4*k+2], ru[4*k+3]);
        ((uint4*)res_row)[k] = w;
    }
    int b = s >> 3;
    int l0 = (s & 7) * T;
    float* ll_row = obsll + ((size_t)a * B0 + b) * L + l0 + t0;
    #pragma unroll
    for (int k = 0; k < 4; ++k) {
        float4 w;
        w.x = ((cmask >> (4*k+0)) & 1) ? pc1a[4*k+0] : pc0a[4*k+0];
        w.y = ((cmask >> (4*k+1)) & 1) ? pc1a[4*k+1] : pc0a[4*k+1];
        w.z = ((cmask >> (4*k+2)) & 1) ? pc1a[4*k+2] : pc0a[4*k+2];
        w.w = ((cmask >> (4*k+3)) & 1) ? pc1a[4*k+3] : pc0a[4*k+3];
        ((float4*)ll_row)[k] = w;
    }
}

// K2+K3 fused: one block per student. Scan all 5 ability rows (exclusive
// prefix over L=8192, kept in registers), then ability-mixture logsumexp.
__global__ __launch_bounds__(1024) void scan_combine_kernel(
    const float* __restrict__ obsll,      // [A][B0][L]
    const __half2* __restrict__ result,   // [A][S][T]
    float* __restrict__ out)              // [B0][L][2]
{
    __shared__ float wsum[16];
    __shared__ float wbase[16];
    int b = blockIdx.x;
    int tid = threadIdx.x;
    int lane = tid & 63, wid = tid >> 6;

    float pf[A][8];
    #pragma unroll
    for (int a = 0; a < A; ++a) {
        const float* base = obsll + ((size_t)a * B0 + b) * L + tid * 8;
        float4 f0 = ((const float4*)base)[0];
        float4 f1 = ((const float4*)base)[1];
        float v[8] = {f0.x, f0.y, f0.z, f0.w, f1.x, f1.y, f1.z, f1.w};
        float ts = 0.0f;
        #pragma unroll
        for (int j = 0; j < 8; ++j) ts += v[j];
        // wave inclusive scan of thread sums
        float incl = ts;
        #pragma unroll
        for (int off = 1; off < 64; off <<= 1) {
            float o = __shfl_up(incl, off);
            if (lane >= off) incl += o;
        }
        if (lane == 63) wsum[wid] = incl;
        __syncthreads();
        if (wid == 0 && lane < 16) {
            float x = wsum[lane];
            #pragma unroll
            for (int off = 1; off < 16; off <<= 1) {
                float o = __shfl_up(x, off);
                if (lane >= off) x += o;
            }
            wbase[lane] = x - wsum[lane];   // exclusive wave base
        }
        __syncthreads();
        float run = wbase[wid] + incl - ts; // exclusive prefix for this thread
        #pragma unroll
        for (int j = 0; j < 8; ++j) { pf[a][j] = run; run += v[j]; }
        __syncthreads();                     // wsum reused next ability
    }

    // load result for the 8 contiguous trials of this thread, all abilities
    int s_sub = b * KCH + (tid >> 7);        // (tid*8) / 1024
    int t0 = (tid * 8) & (T - 1);
    unsigned rr[A][8];
    #pragma unroll
    for (int a = 0; a < A; ++a) {
        const uint4* rp = (const uint4*)(result + ((size_t)a * S + s_sub) * T + t0);
        uint4 qa = rp[0], qb = rp[1];
        rr[a][0] = qa.x; rr[a][1] = qa.y; rr[a][2] = qa.z; rr[a][3] = qa.w;
        rr[a][4] = qb.x; rr[a][5] = qb.y; rr[a][6] = qb.z; rr[a][7] = qb.w;
    }

    float o[16];
    #pragma unroll
    for (int j = 0; j < 8; ++j) {
        float u0[A], u1[A];
        float pm = -INFINITY, m0 = -INFINITY, m1 = -INFINITY;
        #pragma unroll
        for (int a = 0; a < A; ++a) {
            H2U cv_; cv_.u = rr[a][j];
            float2 f = __half22float2(cv_.h);
            float w = pf[a][j];
            u0[a] = f.x + w; u1[a] = f.y + w;
            pm = fmaxf(pm, w);
            m0 = fmaxf(m0, u0[a]);
            m1 = fmaxf(m1, u1[a]);
        }
        float se = 0.0f, s0 = 0.0f, s1 = 0.0f;
        #pragma unroll
        for (int a = 0; a < A; ++a) {
            se += __expf(pf[a][j] - pm);
            s0 += __expf(u0[a] - m0);
            s1 += __expf(u1[a] - m1);
        }
        float lse_ = pm + __logf(se);
        o[2*j]   = m0 + __logf(s0) - lse_;
        o[2*j+1] = m1 + __logf(s1) - lse_;
    }
    float* op = out + 2 * ((size_t)b * L + tid * 8);
    #pragma unroll
    for (int k = 0; k < 4; ++k) {
        float4 w = make_float4(o[4*k], o[4*k+1], o[4*k+2], o[4*k+3]);
        ((float4*)op)[k] = w;
    }
}

extern "C" void kernel_launch(void* const* d_in, const int* in_sizes, int n_in,
                              void* d_out, int out_size, void* d_ws, size_t ws_size,
                              hipStream_t stream) {
    const float* dyn  = (const float*)d_in[0];
    const float* okc  = (const float*)d_in[1];
    const float* oprb = (const float*)d_in[2];
    const float* ab   = (const float*)d_in[3];
    const int* trial  = (const int*)d_in[4];
    const int* prob   = (const int*)d_in[5];
    const int* corr   = (const int*)d_in[6];
    const int* kc     = (const int*)d_in[7];
    float* out = (float*)d_out;

    __half2* result = (__half2*)d_ws;                      // A*S*T half2 = 21 MB
    float* obsll = (float*)((char*)d_ws + (size_t)A * S * T * sizeof(__half2)); // 21 MB

    bkt_filter_kernel<<<(A * S) / WPB, 256, 0, stream>>>(
        dyn, okc, oprb, ab, trial, prob, corr, kc, result, obsll);
    scan_combine_kernel<<<B0, 1024, 0, stream>>>(obsll, result, out);
}

// Round 4
// 45.514 us; speedup vs baseline: 9.4440x; 1.0663x over previous
//
#include <hip/hip_runtime.h>
#include <hip/hip_fp16.h>
#include <math.h>

#define A 5
#define S 1024
#define T 1024
#define KCH 8
#define B0 128
#define L 8192
#define NPROB 1000
#define EPSF 1e-12f
#define CHUNK 16               // time steps per lane
#define WPB 4                  // waves (pairs) per block

__device__ __forceinline__ float sigmoidf_(float x) {
    return 1.0f / (1.0f + __expf(-x));
}

union H2U { unsigned u; __half2 h; };

// K1: BKT forward filter via wave-parallel 2x2-matrix scan.
// One wave per (ability, subsequence) pair; lane i owns steps [16i, 16i+16).
// Emits: result = (p0,p1) predictive probs as half2; pfloc = within-chunk
// exclusive prefix of obs log-lik (f32); sumchunk = per-chunk obs-ll totals.
__global__ __launch_bounds__(256) void bkt_filter_kernel(
    const float* __restrict__ dyn_logits,   // [50][3]
    const float* __restrict__ obs_kc,       // [50][2]
    const float* __restrict__ obs_prob,     // [1000][2]
    const float* __restrict__ abil,         // [5]
    const int*   __restrict__ trial,        // [S][T]
    const int*   __restrict__ problem,      // [S][T]
    const int*   __restrict__ correct,      // [S][T]
    const int*   __restrict__ kc,           // [S]
    __half2* __restrict__ result,           // [A][S][T] (p0,p1)
    float* __restrict__ pfloc,              // [A][S][T] local excl prefix
    float* __restrict__ sumchunk)           // [A][B0][KCH]
{
    __shared__ float s_op[2 * NPROB];       // 8 KB problem-logit table
    for (int i = threadIdx.x; i < 2 * NPROB; i += 256)
        s_op[i] = obs_prob[i];
    __syncthreads();

    int wave = threadIdx.x >> 6;
    int lane = threadIdx.x & 63;
    int pair = blockIdx.x * WPB + wave;     // < A*S always (1280*4 == 5120)
    int a = pair >> 10;
    int s = pair & (S - 1);

    float ability = abil[a];
    int kcs = kc[s];
    float pL = sigmoidf_(dyn_logits[kcs * 3 + 0]);
    float pF = sigmoidf_(dyn_logits[kcs * 3 + 1]);
    float pI = sigmoidf_(dyn_logits[kcs * 3 + 2]);
    float ok0 = obs_kc[kcs * 2 + 0];
    float ok1 = obs_kc[kcs * 2 + 1];
    float t00 = 1.0f - pL, t01 = pF, t10 = pL, t11 = 1.0f - pF;

    int t0 = lane * CHUNK;
    const int4* pv4 = (const int4*)(problem + (size_t)s * T + t0);
    const int4* cv4 = (const int4*)(correct + (size_t)s * T + t0);
    const int4* tv4 = (const int4*)(trial   + (size_t)s * T + t0);
    int4 pv[4], cv[4], tv[4];
    #pragma unroll
    for (int i = 0; i < 4; ++i) { pv[i] = pv4[i]; cv[i] = cv4[i]; tv[i] = tv4[i]; }

    int pj[16];
    int cmask = 0, vmask = 0;
    #pragma unroll
    for (int i = 0; i < 4; ++i) {
        pj[4*i+0] = pv[i].x; pj[4*i+1] = pv[i].y; pj[4*i+2] = pv[i].z; pj[4*i+3] = pv[i].w;
        cmask |= (cv[i].x & 1) << (4*i+0);
        cmask |= (cv[i].y & 1) << (4*i+1);
        cmask |= (cv[i].z & 1) << (4*i+2);
        cmask |= (cv[i].w & 1) << (4*i+3);
        vmask |= (tv[i].x != -1) << (4*i+0);
        vmask |= (tv[i].y != -1) << (4*i+1);
        vmask |= (tv[i].z != -1) << (4*i+2);
        vmask |= (tv[i].w != -1) << (4*i+3);
    }

    // ---- Phase 1: per-lane chunk matrix product (renormalized each step) ----
    float pc0a[16], pc1a[16];
    float p00 = 1.0f, p01 = 0.0f, p10 = 0.0f, p11 = 1.0f;
    #pragma unroll
    for (int j = 0; j < 16; ++j) {
        int p = pj[j];
        bool c = (cmask >> j) & 1;
        float pG = sigmoidf_(ok0 + s_op[2*p]   + ability);
        float pS = sigmoidf_(ok1 + s_op[2*p+1] - ability);
        float pc0 = pG, pc1 = 1.0f - pS;
        pc0a[j] = pc0; pc1a[j] = pc1;
        float lik0 = c ? pc0 : 1.0f - pc0;
        float lik1 = c ? pc1 : 1.0f - pc1;
        // M = T^T * diag(lik);  P <- M * P
        float r0 = lik0 * p00, r1 = lik1 * p10;
        float r2 = lik0 * p01, r3 = lik1 * p11;
        float n00 = t00 * r0 + t01 * r1;
        float n10 = t10 * r0 + t11 * r1;
        float n01 = t00 * r2 + t01 * r3;
        float n11 = t10 * r2 + t11 * r3;
        float inv = __builtin_amdgcn_rcpf(n00 + n01 + n10 + n11);
        p00 = n00 * inv; p01 = n01 * inv; p10 = n10 * inv; p11 = n11 * inv;
    }

    // ---- Phase 2: inclusive shuffle-scan of matrix products over 64 lanes ----
    float q00 = p00, q01 = p01, q10 = p10, q11 = p11;
    #pragma unroll
    for (int off = 1; off < 64; off <<= 1) {
        float o00 = __shfl_up(q00, off);
        float o01 = __shfl_up(q01, off);
        float o10 = __shfl_up(q10, off);
        float o11 = __shfl_up(q11, off);
        if (lane >= off) {
            float n00 = q00 * o00 + q01 * o10;
            float n01 = q00 * o01 + q01 * o11;
            float n10 = q10 * o00 + q11 * o10;
            float n11 = q10 * o01 + q11 * o11;
            float inv = __builtin_amdgcn_rcpf(n00 + n01 + n10 + n11);
            q00 = n00 * inv; q01 = n01 * inv; q10 = n10 * inv; q11 = n11 * inv;
        }
    }
    // exclusive prefix -> alpha at chunk start
    float e00 = __shfl_up(q00, 1), e01 = __shfl_up(q01, 1);
    float e10 = __shfl_up(q10, 1), e11 = __shfl_up(q11, 1);
    if (lane == 0) { e00 = 1.0f; e01 = 0.0f; e10 = 0.0f; e11 = 1.0f; }
    float a0 = e00 * (1.0f - pI) + e01 * pI;
    float a1 = e10 * (1.0f - pI) + e11 * pI;
    {
        float inv = __builtin_amdgcn_rcpf(fmaxf(a0 + a1, EPSF));
        a0 *= inv; a1 *= inv;
    }

    // ---- Phase 3: replay chunk; p0/p1 to store, obs log-lik for the scan ----
    float ll[16];
    float llsum = 0.0f;
    #pragma unroll
    for (int j = 0; j < 16; ++j) {
        float pc0 = pc0a[j], pc1 = pc1a[j];
        bool c = (cmask >> j) & 1;
        bool valid = (vmask >> j) & 1;
        float p_corr = a0 * pc0 + a1 * pc1;
        float p1v = p_corr, p0v = 1.0f - p_corr;
        float py = c ? p1v : p0v;
        float llj = valid ? __logf(fmaxf(py, EPSF)) : 0.0f;
        ll[j] = llj; llsum += llj;
        pc0a[j] = valid ? p0v : 1.0f;     // store probs (1.0 at padding)
        pc1a[j] = valid ? p1v : 1.0f;
        float lik0 = c ? pc0 : 1.0f - pc0;
        float lik1 = c ? pc1 : 1.0f - pc1;
        float qq0 = a0 * lik0, qq1 = a1 * lik1;
        float invq = __builtin_amdgcn_rcpf(fmaxf(qq0 + qq1, EPSF));
        qq0 *= invq; qq1 *= invq;
        a0 = qq0 * t00 + qq1 * t01;
        a1 = qq0 * t10 + qq1 * t11;
    }

    // ---- wave scan of lane obs-ll sums -> exclusive lane base + chunk total
    float incl = llsum;
    #pragma unroll
    for (int off = 1; off < 64; off <<= 1) {
        float o = __shfl_up(incl, off);
        if (lane >= off) incl += o;
    }
    float excl = incl - llsum;
    int b = s >> 3, chunk = s & 7;
    if (lane == 63)
        sumchunk[((size_t)a * B0 + b) * KCH + chunk] = incl;

    // ---- coalesced writes ----
    unsigned ru[16];
    #pragma unroll
    for (int j = 0; j < 16; ++j) {
        H2U cv_;
        cv_.h = __floats2half2_rn(pc0a[j], pc1a[j]);
        ru[j] = cv_.u;
    }
    __half2* res_row = result + ((size_t)pair * T + t0);
    #pragma unroll
    for (int k = 0; k < 4; ++k) {
        uint4 w = make_uint4(ru[4*k], ru[4*k+1], ru[4*k+2], ru[4*k+3]);
        ((uint4*)res_row)[k] = w;
    }
    float* pf_row = pfloc + ((size_t)pair * T + t0);
    float run = excl;
    #pragma unroll
    for (int k = 0; k < 4; ++k) {
        float4 w;
        w.x = run; run += ll[4*k+0];
        w.y = run; run += ll[4*k+1];
        w.z = run; run += ll[4*k+2];
        w.w = run; run += ll[4*k+3];
        ((float4*)pf_row)[k] = w;
    }
}

// K3: one block per (student, chunk) = 1024 blocks. No scan needed: chunk
// bases from sumchunk, local prefix from pfloc, probs from result.
__global__ __launch_bounds__(256) void combine_kernel(
    const float* __restrict__ pfloc,      // [A][S][T]
    const __half2* __restrict__ result,   // [A][S][T]
    const float* __restrict__ sumchunk,   // [A][B0][KCH]
    float* __restrict__ out)              // [B0][L][2]
{
    int s_sub = blockIdx.x;               // = b*KCH + chunk
    int b = s_sub >> 3, chunk = s_sub & 7;
    int t0 = threadIdx.x * 4;

    float pf[A][4];
    float2 pp[A][4];
    #pragma unroll
    for (int a = 0; a < A; ++a) {
        float base = 0.0f;
        for (int k = 0; k < chunk; ++k)
            base += sumchunk[((size_t)a * B0 + b) * KCH + k];
        size_t off = ((size_t)a * S + s_sub) * T + t0;
        float4 f = *(const float4*)(pfloc + off);
        pf[a][0] = f.x + base; pf[a][1] = f.y + base;
        pf[a][2] = f.z + base; pf[a][3] = f.w + base;
        uint4 q = *(const uint4*)(result + off);
        unsigned uu[4] = {q.x, q.y, q.z, q.w};
        #pragma unroll
        for (int j = 0; j < 4; ++j) {
            H2U cv_; cv_.u = uu[j];
            pp[a][j] = __half22float2(cv_.h);
        }
    }

    float o[8];
    #pragma unroll
    for (int j = 0; j < 4; ++j) {
        float pm = -INFINITY;
        #pragma unroll
        for (int a = 0; a < A; ++a) pm = fmaxf(pm, pf[a][j]);
        float Se = 0.0f, S0 = 0.0f, S1 = 0.0f;
        #pragma unroll
        for (int a = 0; a < A; ++a) {
            float e = __expf(pf[a][j] - pm);
            Se += e;
            S0 += e * pp[a][j].x;
            S1 += e * pp[a][j].y;
        }
        float ls = __logf(Se);
        o[2*j]   = __logf(S0) - ls;
        o[2*j+1] = __logf(S1) - ls;
    }
    float* op = out + 2 * ((size_t)b * L + chunk * T + t0);
    ((float4*)op)[0] = make_float4(o[0], o[1], o[2], o[3]);
    ((float4*)op)[1] = make_float4(o[4], o[5], o[6], o[7]);
}

extern "C" void kernel_launch(void* const* d_in, const int* in_sizes, int n_in,
                              void* d_out, int out_size, void* d_ws, size_t ws_size,
                              hipStream_t stream) {
    const float* dyn  = (const float*)d_in[0];
    const float* okc  = (const float*)d_in[1];
    const float* oprb = (const float*)d_in[2];
    const float* ab   = (const float*)d_in[3];
    const int* trial  = (const int*)d_in[4];
    const int* prob   = (const int*)d_in[5];
    const int* corr   = (const int*)d_in[6];
    const int* kc     = (const int*)d_in[7];
    float* out = (float*)d_out;

    __half2* result = (__half2*)d_ws;                               // 21 MB
    float* pfloc = (float*)((char*)d_ws + (size_t)A * S * T * 4);   // 21 MB
    float* sumchunk = pfloc + (size_t)A * S * T;                    // 20 KB

    bkt_filter_kernel<<<(A * S) / WPB, 256, 0, stream>>>(
        dyn, okc, oprb, ab, trial, prob, corr, kc, result, pfloc, sumchunk);
    combine_kernel<<<B0 * KCH, 256, 0, stream>>>(pfloc, result, sumchunk, out);
}

// Round 5
// 39.414 us; speedup vs baseline: 10.9057x; 1.1548x over previous
//
#include <hip/hip_runtime.h>
#include <hip/hip_fp16.h>
#include <math.h>

#define A 5
#define S 1024
#define T 1024
#define KCH 8
#define B0 128
#define L 8192
#define NPROB 1000
#define EPSF 1e-12f
#define CHUNK 8                // time steps per lane
#define PPB 2                  // pairs per block (2 waves each -> 256 threads)

__device__ __forceinline__ float sigmoidf_(float x) {
    return 1.0f / (1.0f + __expf(-x));
}

union H2U { unsigned u; __half2 h; };

// K1: BKT forward filter via wave-parallel 2x2-matrix scan.
// TWO waves per (ability, subsequence) pair; lane i of wave-half h owns
// steps [ (h*64+i)*8, +8 ).  Emits: result = (p0,p1) predictive probs as
// half2; pfloc = within-subsequence exclusive prefix of obs log-lik (f32);
// sumchunk = per-subsequence obs-ll totals.
__global__ __launch_bounds__(256) void bkt_filter_kernel(
    const float* __restrict__ dyn_logits,   // [50][3]
    const float* __restrict__ obs_kc,       // [50][2]
    const float* __restrict__ obs_prob,     // [1000][2]
    const float* __restrict__ abil,         // [5]
    const int*   __restrict__ trial,        // [S][T]
    const int*   __restrict__ problem,      // [S][T]
    const int*   __restrict__ correct,      // [S][T]
    const int*   __restrict__ kc,           // [S]
    __half2* __restrict__ result,           // [A][S][T] (p0,p1)
    float* __restrict__ pfloc,              // [A][S][T] local excl prefix
    float* __restrict__ sumchunk)           // [A][B0][KCH]
{
    __shared__ float2 s_e[NPROB];           // 8 KB: (exp(-op0), exp(+op1))
    __shared__ float  s_m0[PPB][4];         // wave-0 total chunk matrix
    __shared__ float  s_llw[PPB];           // wave-0 total obs-ll

    for (int i = threadIdx.x; i < NPROB; i += 256) {
        float2 op = ((const float2*)obs_prob)[i];
        s_e[i] = make_float2(__expf(-op.x), __expf(op.y));
    }
    __syncthreads();

    int wv = threadIdx.x >> 6;
    int lane = threadIdx.x & 63;
    int pib = wv >> 1;                      // pair within block
    int half = wv & 1;                      // which T/2 half this wave owns
    int pair = blockIdx.x * PPB + pib;      // < A*S
    int a = pair >> 10;
    int s = pair & (S - 1);

    float ability = abil[a];
    int kcs = kc[s];
    float pL = sigmoidf_(dyn_logits[kcs * 3 + 0]);
    float pF = sigmoidf_(dyn_logits[kcs * 3 + 1]);
    float pI = sigmoidf_(dyn_logits[kcs * 3 + 2]);
    float ok0 = obs_kc[kcs * 2 + 0];
    float ok1 = obs_kc[kcs * 2 + 1];
    float t00 = 1.0f - pL, t01 = pF, t10 = pL, t11 = 1.0f - pF;
    // sigmoid strength-reduction constants (wave-uniform)
    float c0 = __expf(-ok0 - ability);      // pc0 = rcp(1 + e.x*c0)
    float c1 = __expf( ok1 - ability);      // pc1 = rcp(1 + e.y*c1)

    int t0 = half * (T / 2) + lane * CHUNK;
    const int4* pv4 = (const int4*)(problem + (size_t)s * T + t0);
    const int4* cv4 = (const int4*)(correct + (size_t)s * T + t0);
    const int4* tv4 = (const int4*)(trial   + (size_t)s * T + t0);
    int4 pva = pv4[0], pvb = pv4[1];
    int4 cva = cv4[0], cvb = cv4[1];
    int4 tva = tv4[0], tvb = tv4[1];

    int pj[8] = {pva.x, pva.y, pva.z, pva.w, pvb.x, pvb.y, pvb.z, pvb.w};
    int cj[8] = {cva.x, cva.y, cva.z, cva.w, cvb.x, cvb.y, cvb.z, cvb.w};
    int vj[8] = {tva.x, tva.y, tva.z, tva.w, tvb.x, tvb.y, tvb.z, tvb.w};
    int cmask = 0, vmask = 0;
    #pragma unroll
    for (int j = 0; j < 8; ++j) {
        cmask |= (cj[j] & 1) << j;
        vmask |= (vj[j] != -1) << j;
    }

    // ---- Phase 1: per-lane chunk matrix product (normalize every 4) ----
    float pc0a[8], pc1a[8];
    float p00 = 1.0f, p01 = 0.0f, p10 = 0.0f, p11 = 1.0f;
    #pragma unroll
    for (int j = 0; j < 8; ++j) {
        float2 e = s_e[pj[j]];
        float pc0 = __builtin_amdgcn_rcpf(1.0f + e.x * c0);
        float pc1 = __builtin_amdgcn_rcpf(1.0f + e.y * c1);
        pc0a[j] = pc0; pc1a[j] = pc1;
        bool c = (cmask >> j) & 1;
        float lik0 = c ? pc0 : 1.0f - pc0;
        float lik1 = c ? pc1 : 1.0f - pc1;
        // P <- (T^T * diag(lik)) * P
        float r0 = lik0 * p00, r1 = lik1 * p10;
        float r2 = lik0 * p01, r3 = lik1 * p11;
        p00 = t00 * r0 + t01 * r1;
        p10 = t10 * r0 + t11 * r1;
        p01 = t00 * r2 + t01 * r3;
        p11 = t10 * r2 + t11 * r3;
        if ((j & 3) == 3) {
            float inv = __builtin_amdgcn_rcpf(p00 + p01 + p10 + p11);
            p00 *= inv; p01 *= inv; p10 *= inv; p11 *= inv;
        }
    }

    // ---- Phase 2a: intra-wave inclusive matrix scan over 64 lanes ----
    float q00 = p00, q01 = p01, q10 = p10, q11 = p11;
    #pragma unroll
    for (int off = 1; off < 64; off <<= 1) {
        float o00 = __shfl_up(q00, off);
        float o01 = __shfl_up(q01, off);
        float o10 = __shfl_up(q10, off);
        float o11 = __shfl_up(q11, off);
        if (lane >= off) {
            float n00 = q00 * o00 + q01 * o10;
            float n01 = q00 * o01 + q01 * o11;
            float n10 = q10 * o00 + q11 * o10;
            float n11 = q10 * o01 + q11 * o11;
            float inv = __builtin_amdgcn_rcpf(n00 + n01 + n10 + n11);
            q00 = n00 * inv; q01 = n01 * inv; q10 = n10 * inv; q11 = n11 * inv;
        }
    }
    if (half == 0 && lane == 63) {
        s_m0[pib][0] = q00; s_m0[pib][1] = q01;
        s_m0[pib][2] = q10; s_m0[pib][3] = q11;
    }
    __syncthreads();

    // ---- Phase 2b: exclusive prefix (+ wave-0 total for the upper half) ----
    float e00 = __shfl_up(q00, 1), e01 = __shfl_up(q01, 1);
    float e10 = __shfl_up(q10, 1), e11 = __shfl_up(q11, 1);
    if (lane == 0) { e00 = 1.0f; e01 = 0.0f; e10 = 0.0f; e11 = 1.0f; }
    if (half == 1) {
        float m00 = s_m0[pib][0], m01 = s_m0[pib][1];
        float m10 = s_m0[pib][2], m11 = s_m0[pib][3];
        float n00 = e00 * m00 + e01 * m10;
        float n01 = e00 * m01 + e01 * m11;
        float n10 = e10 * m00 + e11 * m10;
        float n11 = e10 * m01 + e11 * m11;
        e00 = n00; e01 = n01; e10 = n10; e11 = n11;
    }
    float a0 = e00 * (1.0f - pI) + e01 * pI;
    float a1 = e10 * (1.0f - pI) + e11 * pI;
    {
        float inv = __builtin_amdgcn_rcpf(fmaxf(a0 + a1, EPSF));
        a0 *= inv; a1 *= inv;
    }

    // ---- Phase 3: replay chunk; probs to store, obs log-lik for the scan ----
    float ll[8];
    float llsum = 0.0f;
    #pragma unroll
    for (int j = 0; j < 8; ++j) {
        float pc0 = pc0a[j], pc1 = pc1a[j];
        bool c = (cmask >> j) & 1;
        bool valid = (vmask >> j) & 1;
        float p_corr = a0 * pc0 + a1 * pc1;
        float p1v = p_corr, p0v = 1.0f - p_corr;
        float py = c ? p1v : p0v;
        float llj = valid ? __logf(fmaxf(py, EPSF)) : 0.0f;
        ll[j] = llj; llsum += llj;
        pc0a[j] = valid ? p0v : 1.0f;     // probs to store (1.0 at padding)
        pc1a[j] = valid ? p1v : 1.0f;
        float lik0 = c ? pc0 : 1.0f - pc0;
        float lik1 = c ? pc1 : 1.0f - pc1;
        float qq0 = a0 * lik0, qq1 = a1 * lik1;
        float invq = __builtin_amdgcn_rcpf(fmaxf(qq0 + qq1, EPSF));
        qq0 *= invq; qq1 *= invq;
        a0 = qq0 * t00 + qq1 * t01;
        a1 = qq0 * t10 + qq1 * t11;
    }

    // ---- obs-ll scan: intra-wave + cross-wave base ----
    float incl = llsum;
    #pragma unroll
    for (int off = 1; off < 64; off <<= 1) {
        float o = __shfl_up(incl, off);
        if (lane >= off) incl += o;
    }
    float excl = incl - llsum;
    if (half == 0 && lane == 63) s_llw[pib] = incl;
    __syncthreads();
    int b = s >> 3, chunk = s & 7;
    if (half == 1) {
        float w0 = s_llw[pib];
        excl += w0;
        if (lane == 63)
            sumchunk[((size_t)a * B0 + b) * KCH + chunk] = w0 + incl;
    }

    // ---- coalesced writes ----
    unsigned ru[8];
    #pragma unroll
    for (int j = 0; j < 8; ++j) {
        H2U cv_;
        cv_.h = __floats2half2_rn(pc0a[j], pc1a[j]);
        ru[j] = cv_.u;
    }
    __half2* res_row = result + ((size_t)pair * T + t0);
    ((uint4*)res_row)[0] = make_uint4(ru[0], ru[1], ru[2], ru[3]);
    ((uint4*)res_row)[1] = make_uint4(ru[4], ru[5], ru[6], ru[7]);

    float* pf_row = pfloc + ((size_t)pair * T + t0);
    float run = excl;
    float pw[8];
    #pragma unroll
    for (int j = 0; j < 8; ++j) { pw[j] = run; run += ll[j]; }
    ((float4*)pf_row)[0] = make_float4(pw[0], pw[1], pw[2], pw[3]);
    ((float4*)pf_row)[1] = make_float4(pw[4], pw[5], pw[6], pw[7]);
}

// K3: one block per (student, chunk) = 1024 blocks. No scan needed: chunk
// bases from sumchunk, local prefix from pfloc, probs from result.
__global__ __launch_bounds__(256) void combine_kernel(
    const float* __restrict__ pfloc,      // [A][S][T]
    const __half2* __restrict__ result,   // [A][S][T]
    const float* __restrict__ sumchunk,   // [A][B0][KCH]
    float* __restrict__ out)              // [B0][L][2]
{
    int s_sub = blockIdx.x;               // = b*KCH + chunk
    int b = s_sub >> 3, chunk = s_sub & 7;
    int t0 = threadIdx.x * 4;

    float pf[A][4];
    float2 pp[A][4];
    #pragma unroll
    for (int a = 0; a < A; ++a) {
        float base = 0.0f;
        for (int k = 0; k < chunk; ++k)
            base += sumchunk[((size_t)a * B0 + b) * KCH + k];
        size_t off = ((size_t)a * S + s_sub) * T + t0;
        float4 f = *(const float4*)(pfloc + off);
        pf[a][0] = f.x + base; pf[a][1] = f.y + base;
        pf[a][2] = f.z + base; pf[a][3] = f.w + base;
        uint4 q = *(const uint4*)(result + off);
        unsigned uu[4] = {q.x, q.y, q.z, q.w};
        #pragma unroll
        for (int j = 0; j < 4; ++j) {
            H2U cv_; cv_.u = uu[j];
            pp[a][j] = __half22float2(cv_.h);
        }
    }

    float o[8];
    #pragma unroll
    for (int j = 0; j < 4; ++j) {
        float pm = -INFINITY;
        #pragma unroll
        for (int a = 0; a < A; ++a) pm = fmaxf(pm, pf[a][j]);
        float Se = 0.0f, S0 = 0.0f, S1 = 0.0f;
        #pragma unroll
        for (int a = 0; a < A; ++a) {
            float e = __expf(pf[a][j] - pm);
            Se += e;
            S0 += e * pp[a][j].x;
            S1 += e * pp[a][j].y;
        }
        float ls = __logf(Se);
        o[2*j]   = __logf(S0) - ls;
        o[2*j+1] = __logf(S1) - ls;
    }
    float* op = out + 2 * ((size_t)b * L + chunk * T + t0);
    ((float4*)op)[0] = make_float4(o[0], o[1], o[2], o[3]);
    ((float4*)op)[1] = make_float4(o[4], o[5], o[6], o[7]);
}

extern "C" void kernel_launch(void* const* d_in, const int* in_sizes, int n_in,
                              void* d_out, int out_size, void* d_ws, size_t ws_size,
                              hipStream_t stream) {
    const float* dyn  = (const float*)d_in[0];
    const float* okc  = (const float*)d_in[1];
    const float* oprb = (const float*)d_in[2];
    const float* ab   = (const float*)d_in[3];
    const int* trial  = (const int*)d_in[4];
    const int* prob   = (const int*)d_in[5];
    const int* corr   = (const int*)d_in[6];
    const int* kc     = (const int*)d_in[7];
    float* out = (float*)d_out;

    __half2* result = (__half2*)d_ws;                               // 21 MB
    float* pfloc = (float*)((char*)d_ws + (size_t)A * S * T * 4);   // 21 MB
    float* sumchunk = pfloc + (size_t)A * S * T;                    // 20 KB

    bkt_filter_kernel<<<(A * S) / PPB, 256, 0, stream>>>(
        dyn, okc, oprb, ab, trial, prob, corr, kc, result, pfloc, sumchunk);
    combine_kernel<<<B0 * KCH, 256, 0, stream>>>(pfloc, result, sumchunk, out);
}